// Round 10
// baseline (52.006 us; speedup 1.0000x reference)
//
#include <hip/hip_runtime.h>
#include <math.h>

// Segment mean via block-local counting sort + run-gather reduce.
//   K1: DENSE streaming of edge_x rows (float4, full-line requests) -> s_val
//       in LDS; dst via dense int4 into registers; LDS histogram + scan
//       (boff row from scan regs); LDS counting sort; dense uint4 writeout.
//   K2: one block per bucket; thread t gathers chunk t's run (avg 16
//       consecutive u32, 1-2 lines, L1-cached), packed-double LDS accumulate.
// Theory: all prior variants were pinned ~51us by the 32B-stride sector-
// request rate of the edge_x column gather; dense float4 streaming trades
// bytes for 4x fewer memory transactions.
// Fallback to packed-f64-atomic scatter if ws is too small.

#define PACK_MAGIC 4294967296.0   // 2^32
#define NB 391                    // ceil(100000 / 256)
#define BSHIFT 8
#define SNODES 256
#define NC 512                    // chunks (= K1 blocks; K2 threads)
#define CMAXR 6400                // max chunkR (LDS arrays sized to this)
#define T1 1024                   // K1 block size (16 waves)
#define DPT4 2                    // int4 dst loads per thread: 4*T1*DPT4 >= chunkR
#define T2 512                    // K2 block size (one chunk per thread)

__device__ __forceinline__ unsigned pack_pair(float v, int local) {
    unsigned b = __float_as_uint(v);
    b = (b + 0x80u) & 0xFFFFFF00u;           // round mantissa to 15 bits
    return b | (unsigned)local;
}

// K1: dense stream -> hist -> scan(+boff) -> LDS sort -> dense writeout
__global__ void __launch_bounds__(T1)
sort_kernel(const float* __restrict__ edge_x,
            const int* __restrict__ dst,
            unsigned* __restrict__ pairs,
            int* __restrict__ boff,
            int n_edges, int chunkR) {
    __shared__ unsigned s_data[CMAXR];
    __shared__ float s_val[CMAXR];
    __shared__ int h[NB];     // chunk bucket counts
    __shared__ int cnt[NB];   // cursors (start at exclusive-scan positions)

    int tid = threadIdx.x, blk = blockIdx.x;
    long beg = (long)blk * chunkR;
    long rem = (long)n_edges - beg;
    int chunkN = (rem < 0) ? 0 : (int)min((long)chunkR, rem);

    // dst: dense int4 loads into registers (rows r0 = g*4 .. g*4+3)
    int4 rd4[DPT4];
#pragma unroll
    for (int k = 0; k < DPT4; ++k) {
        int g = tid + k * T1;          // int4 index within chunk
        int r0 = g * 4;
        if (r0 + 3 < chunkN) {
            rd4[k] = *reinterpret_cast<const int4*>(dst + beg + r0);
        } else {
            rd4[k].x = (r0 + 0 < chunkN) ? dst[beg + r0 + 0] : -1;
            rd4[k].y = (r0 + 1 < chunkN) ? dst[beg + r0 + 1] : -1;
            rd4[k].z = (r0 + 2 < chunkN) ? dst[beg + r0 + 2] : -1;
            rd4[k].w = (r0 + 3 < chunkN) ? dst[beg + r0 + 3] : -1;
        }
    }

    // edge_x: DENSE float4 stream over the chunk's rows; col0 lives in
    // float4 #g (g even) at .x, for row g/2. All requests contiguous.
    {
        const float4* ex4 = reinterpret_cast<const float4*>(edge_x) + beg * 2;
        int cap = 2 * chunkN;          // float4s covering chunkN rows
        for (int g = tid; g < cap; g += T1) {
            float4 v = ex4[g];
            if (!(g & 1)) s_val[g >> 1] = v.x;
        }
    }

    for (int b = tid; b < NB; b += T1) h[b] = 0;
    __syncthreads();

    // histogram from dst registers
#pragma unroll
    for (int k = 0; k < DPT4; ++k) {
        if (rd4[k].x >= 0) atomicAdd(&h[rd4[k].x >> BSHIFT], 1);
        if (rd4[k].y >= 0) atomicAdd(&h[rd4[k].y >> BSHIFT], 1);
        if (rd4[k].z >= 0) atomicAdd(&h[rd4[k].z >> BSHIFT], 1);
        if (rd4[k].w >= 0) atomicAdd(&h[rd4[k].w >> BSHIFT], 1);
    }
    __syncthreads();

    // wave 0: exclusive scan h -> cnt, store boff row from scan registers
    if (tid < 64) {
        int lane = tid;
        const int K = (NB + 63) / 64;  // 7
        int vals[7];
        int local = 0;
#pragma unroll
        for (int k = 0; k < K; ++k) {
            int idx = lane * K + k;
            int v = (idx < NB) ? h[idx] : 0;
            vals[k] = v; local += v;
        }
        int s = local;
        for (int off = 1; off < 64; off <<= 1) {
            int t = __shfl_up(s, off);
            if (lane >= off) s += t;
        }
        int ex = s - local;
        int* row = boff + (size_t)blk * (NB + 1);
#pragma unroll
        for (int k = 0; k < K; ++k) {
            int idx = lane * K + k;
            if (idx < NB) { cnt[idx] = ex; row[idx] = ex; }
            ex += vals[k];
        }
        if (lane == 0) row[NB] = chunkN;
    }
    __syncthreads();

    // stage into sorted LDS positions; values come from s_val (LDS)
#pragma unroll
    for (int k = 0; k < DPT4; ++k) {
        int r0 = (tid + k * T1) * 4;
        int d;
        d = rd4[k].x;
        if (d >= 0) {
            int p = atomicAdd(&cnt[d >> BSHIFT], 1);
            s_data[p] = pack_pair(s_val[r0 + 0], d & (SNODES - 1));
        }
        d = rd4[k].y;
        if (d >= 0) {
            int p = atomicAdd(&cnt[d >> BSHIFT], 1);
            s_data[p] = pack_pair(s_val[r0 + 1], d & (SNODES - 1));
        }
        d = rd4[k].z;
        if (d >= 0) {
            int p = atomicAdd(&cnt[d >> BSHIFT], 1);
            s_data[p] = pack_pair(s_val[r0 + 2], d & (SNODES - 1));
        }
        d = rd4[k].w;
        if (d >= 0) {
            int p = atomicAdd(&cnt[d >> BSHIFT], 1);
            s_data[p] = pack_pair(s_val[r0 + 3], d & (SNODES - 1));
        }
    }
    __syncthreads();

    // dense coalesced writeout (uint4)
    unsigned* outp = pairs + (size_t)blk * chunkR;
    for (int p = tid * 4; p < chunkN; p += T1 * 4) {
        if (p + 4 <= chunkN) {
            *reinterpret_cast<uint4*>(outp + p) =
                *reinterpret_cast<const uint4*>(&s_data[p]);
        } else {
            for (int q = p; q < chunkN; ++q) outp[q] = s_data[q];
        }
    }
}

// K2: one block per bucket; thread t gathers chunk t's run, LDS accumulate
__global__ void __launch_bounds__(T2)
reduce_kernel(const unsigned* __restrict__ pairs,
              const int* __restrict__ boff,
              float* __restrict__ out, int n_nodes, int chunkR) {
    __shared__ double acc[SNODES];
    int b = blockIdx.x, tid = threadIdx.x;
    for (int i = tid; i < SNODES; i += T2) acc[i] = 0.0;
    __syncthreads();

    for (int c = tid; c < NC; c += T2) {
        const int* row = boff + (size_t)c * (NB + 1);
        int s = row[b];
        int e = row[b + 1];
        const unsigned* src = pairs + (size_t)c * chunkR;
        for (int j = s; j < e; ++j) {
            unsigned p = src[j];
            float v = __uint_as_float(p & 0xFFFFFF00u);
            atomicAdd(&acc[p & 0xFFu], (double)v + PACK_MAGIC);
        }
    }
    __syncthreads();

    int node0 = b << BSHIFT;
    for (int i = tid; i < SNODES; i += T2) {
        int node = node0 + i;
        if (node < n_nodes) {
            double x = acc[i];
            double c2 = nearbyint(x * (1.0 / PACK_MAGIC));
            double s2 = x - c2 * PACK_MAGIC;
            out[node] = (c2 > 0.0) ? (float)(s2 / c2) : 0.0f;
        }
    }
}

// ---------- fallback: packed-f64 atomic path ----------

__global__ void zero_ws_kernel(double* __restrict__ ws, int n) {
    int i = blockIdx.x * blockDim.x + threadIdx.x;
    int stride = gridDim.x * blockDim.x;
    for (; i < n; i += stride) ws[i] = 0.0;
}

__global__ void scatter_atomic_kernel(const float* __restrict__ edge_x,
                                      const int* __restrict__ dst,
                                      double* __restrict__ part,
                                      int n_edges, int n_nodes, int r_mask) {
    int t = blockIdx.x * blockDim.x + threadIdx.x;
    int basei = t * 4;
    double* my = part + (size_t)(blockIdx.x & r_mask) * (size_t)n_nodes;
    if (basei + 3 < n_edges) {
        int4 d4 = *reinterpret_cast<const int4*>(dst + basei);
        float v0 = edge_x[(size_t)(basei + 0) * 8];
        float v1 = edge_x[(size_t)(basei + 1) * 8];
        float v2 = edge_x[(size_t)(basei + 2) * 8];
        float v3 = edge_x[(size_t)(basei + 3) * 8];
        atomicAdd(&my[d4.x], (double)v0 + PACK_MAGIC);
        atomicAdd(&my[d4.y], (double)v1 + PACK_MAGIC);
        atomicAdd(&my[d4.z], (double)v2 + PACK_MAGIC);
        atomicAdd(&my[d4.w], (double)v3 + PACK_MAGIC);
    } else {
        for (int i = basei; i < n_edges; ++i) {
            float v = edge_x[(size_t)i * 8];
            atomicAdd(&my[dst[i]], (double)v + PACK_MAGIC);
        }
    }
}

__global__ void finalize_atomic_kernel(const double* __restrict__ part,
                                       float* __restrict__ out, int n_nodes, int R) {
    int i = blockIdx.x * blockDim.x + threadIdx.x;
    if (i >= n_nodes) return;
    double x = 0.0;
    for (int r = 0; r < R; ++r) x += part[(size_t)r * n_nodes + i];
    double c = nearbyint(x * (1.0 / PACK_MAGIC));
    double s = x - c * PACK_MAGIC;
    out[i] = (c > 0.0) ? (float)(s / c) : 0.0f;
}

// ---------- launch ----------

extern "C" void kernel_launch(void* const* d_in, const int* in_sizes, int n_in,
                              void* d_out, int out_size, void* d_ws, size_t ws_size,
                              hipStream_t stream) {
    const float* edge_x = (const float*)d_in[0];
    const int*   dst    = (const int*)d_in[1];
    float* out = (float*)d_out;

    const int n_nodes = out_size;        // 100000
    const int n_edges = in_sizes[1];     // 3200000

    // chunk rounded to multiple of 4 (int4/uint4/float4 alignment)
    int chunkR = (((n_edges + NC - 1) / NC) + 3) & ~3;

    size_t pairs_bytes = (size_t)NC * chunkR * sizeof(unsigned);
    size_t boff_bytes  = (size_t)NC * (NB + 1) * sizeof(int);
    size_t need = pairs_bytes + boff_bytes;

    if (ws_size >= need && n_nodes <= NB * SNODES &&
        chunkR <= CMAXR && chunkR <= 4 * T1 * DPT4) {
        unsigned* pairs = (unsigned*)d_ws;
        int* boff = (int*)((char*)d_ws + pairs_bytes);

        sort_kernel<<<NC, T1, 0, stream>>>(edge_x, dst, pairs, boff,
                                           n_edges, chunkR);
        reduce_kernel<<<NB, T2, 0, stream>>>(pairs, boff, out, n_nodes, chunkR);
    } else {
        int R = 1;
        while (R < 8 && (size_t)(R * 2) * (size_t)n_nodes * sizeof(double) <= ws_size) R *= 2;
        double* part = (double*)d_ws;
        {
            int n = R * n_nodes;
            int blocks = min((n + 255) / 256, 2048);
            zero_ws_kernel<<<blocks, 256, 0, stream>>>(part, n);
        }
        {
            int nthreads = (n_edges + 3) / 4;
            int blocks = (nthreads + 255) / 256;
            scatter_atomic_kernel<<<blocks, 256, 0, stream>>>(edge_x, dst, part,
                                                              n_edges, n_nodes, R - 1);
        }
        {
            int blocks = (n_nodes + 255) / 256;
            finalize_atomic_kernel<<<blocks, 256, 0, stream>>>(part, out, n_nodes, R);
        }
    }
}